// Round 8
// baseline (157.912 us; speedup 1.0000x reference)
//
#include <hip/hip_runtime.h>
#include <hip/hip_fp16.h>

#define CC 256   // input channels
#define OO 256   // output channels
#define HH 64
#define WW 64
#define HWN 4096 // H*W
#define MPB 32   // pixels per block
#define VST 264  // val_lds row stride in halfs (528B: odd 16B-stride -> 2-way banks)
#define VOFF (MPB * VST)   // halfs per val buffer

typedef _Float16 half8 __attribute__((ext_vector_type(8)));
typedef _Float16 half2v __attribute__((ext_vector_type(2)));
typedef float f32x4 __attribute__((ext_vector_type(4)));

__device__ __forceinline__ half2v u2h(unsigned u) {
  half2v h; __builtin_memcpy(&h, &u, 4); return h;
}
__device__ __forceinline__ unsigned h2u(half2v h) {
  unsigned u; __builtin_memcpy(&u, &h, 4); return u;
}
__device__ __forceinline__ unsigned short f2h(float f) {
  _Float16 h = (_Float16)f;
  unsigned short us; __builtin_memcpy(&us, &h, 2);
  return us;
}
__device__ __forceinline__ unsigned dupu(unsigned short us) {
  return ((unsigned)us << 16) | us;
}
__device__ __forceinline__ unsigned pk2(float a, float b) {
  half2v h = {(_Float16)a, (_Float16)b};
  return h2u(h);
}

// raw barrier: NO vmcnt drain (in-flight global loads survive the barrier);
// explicit lgkm wait orders ds_write -> barrier -> ds_read.
__device__ __forceinline__ void vsync() {
  __builtin_amdgcn_sched_barrier(0);
  asm volatile("s_waitcnt lgkmcnt(0)" ::: "memory");
  __builtin_amdgcn_s_barrier();
  __builtin_amdgcn_sched_barrier(0);
}

// ---------- fused prep (UNCHANGED — it moves only ~29 MB; ~5-10 us) ----------
__global__ __launch_bounds__(256) void prep_kernel(
    const float* __restrict__ x, const float* __restrict__ w,
    _Float16* __restrict__ xt, _Float16* __restrict__ wt) {
  const int bid = blockIdx.x;
  const int tid = threadIdx.x;
  if (bid < 1024) {
    __shared__ float tile[64][65];   // [hw][c]
    const int n  = bid >> 8;
    const int c0 = ((bid >> 6) & 3) * 64;
    const int s0 = (bid & 63) * 64;
    {
      int r  = tid >> 2;          // channel row 0..63
      int sc = (tid & 3) * 16;    // hw start
      const float* xp = x + ((size_t)(n * CC + c0 + r)) * HWN + s0 + sc;
      float4 va = *(const float4*)(xp);
      float4 vb = *(const float4*)(xp + 4);
      float4 vc = *(const float4*)(xp + 8);
      float4 vd = *(const float4*)(xp + 12);
      tile[sc + 0][r]  = va.x;  tile[sc + 1][r]  = va.y;
      tile[sc + 2][r]  = va.z;  tile[sc + 3][r]  = va.w;
      tile[sc + 4][r]  = vb.x;  tile[sc + 5][r]  = vb.y;
      tile[sc + 6][r]  = vb.z;  tile[sc + 7][r]  = vb.w;
      tile[sc + 8][r]  = vc.x;  tile[sc + 9][r]  = vc.y;
      tile[sc + 10][r] = vc.z;  tile[sc + 11][r] = vc.w;
      tile[sc + 12][r] = vd.x;  tile[sc + 13][r] = vd.y;
      tile[sc + 14][r] = vd.z;  tile[sc + 15][r] = vd.w;
    }
    __syncthreads();
    {
      int s  = tid >> 2;          // hw row
      int cg = (tid & 3) * 16;    // c start
      uint4 u0, u1;
      u0.x = pk2(tile[s][cg + 0],  tile[s][cg + 1]);
      u0.y = pk2(tile[s][cg + 2],  tile[s][cg + 3]);
      u0.z = pk2(tile[s][cg + 4],  tile[s][cg + 5]);
      u0.w = pk2(tile[s][cg + 6],  tile[s][cg + 7]);
      u1.x = pk2(tile[s][cg + 8],  tile[s][cg + 9]);
      u1.y = pk2(tile[s][cg + 10], tile[s][cg + 11]);
      u1.z = pk2(tile[s][cg + 12], tile[s][cg + 13]);
      u1.w = pk2(tile[s][cg + 14], tile[s][cg + 15]);
      _Float16* op = xt + ((size_t)(n * HWN + s0 + s)) * CC + c0 + cg;
      *(uint4*)(op)     = u0;
      *(uint4*)(op + 8) = u1;
    }
  } else {
    __shared__ _Float16 wrow[9][264];
    const int o = bid - 1024;
    const float* wp = w + (size_t)o * (CC * 9);
    float v[9];
#pragma unroll
    for (int k = 0; k < 9; ++k) v[k] = wp[tid * 9 + k];
#pragma unroll
    for (int k = 0; k < 9; ++k) wrow[k][tid] = (_Float16)v[k];
    __syncthreads();
    for (int r = tid; r < 9 * 64; r += 256) {
      int k  = r >> 6;
      int c4 = (r & 63) * 4;
      *(uint2*)(wt + (size_t)k * (OO * CC) + (size_t)o * CC + c4) =
          *(const uint2*)(&wrow[k][c4]);
    }
  }
}

// ------------- deform-sample + MFMA GEMM: B pinned in regs, 1 barrier/tap (race-free) -------------
// grid 512 x 512 thr (8 waves). Block: 32 px x 256 o x 256 c; wave = 32px x 32o.
// Per tap k:  issue B[k] loads -> vsync -> sample(k+1)->val[nxt] -> pin(B) -> GEMM<-val[cur].
// RACE-FREE single barrier: writes to nxt and reads of cur BOTH sit after vsync_k;
// the next overwrite of cur (iter k+1's sample) is fenced by vsync_{k+1}.
// (r7 bug: sample was BEFORE vsync -> fast wave overwrote cur while slow wave read it.)
// B loads cross the barrier in flight (lgkm-only drain); asm pins force register
// residency (r6's VGPR=56 sinking bug); sample's global loads issue before the
// GEMM so their L2 latency hides under 32 MFMAs.
// LDS 38.4 KB -> 2 blocks/CU (grid-limited) = 16 waves/CU; two barrier domains.
// XCD decode: xcd=bx&7 -> image xcd>>1, img-half xcd&1; group bx>>3 (0..63).
__global__ __launch_bounds__(512, 4) void deform_mfma_kernel(
    const _Float16* __restrict__ xt,   // [4][4096][256] fp16
    const _Float16* __restrict__ wt,   // [9][256][256] fp16 ([k][o][c])
    const float* __restrict__ off,
    float* __restrict__ out) {
  __shared__ __align__(16) _Float16 val_lds[2 * VOFF];   // 33792 B [buf][p][c]
  __shared__ ushort4 s_po[MPB * 9];   // clamped flat corner row offsets (2304 B)
  __shared__ ushort4 s_pw[MPB * 9];   // fp16 bilinear weights (2304 B)

  const int tid  = threadIdx.x;
  const int lane = tid & 63;
  const int wv   = tid >> 6;          // 0..7 -> o-slice wv*32
  const int n15  = lane & 15;
  const int quad = lane >> 4;

  const int bx  = blockIdx.x;
  const int xcd = bx & 7;
  const int nb  = xcd >> 1;                              // image
  const int hw0 = (((xcd & 1) << 6) | (bx >> 3)) * MPB;  // pixel group base

  const int o0 = wv * 32;             // wave's o-slice

  // ---- precompute per-(pixel,tap) sampling params (288 entries) ----
  if (tid < MPB * 9) {
    int e = tid;
    int p = e / 9;
    int k = e - p * 9;
    int hw = hw0 + p;
    int h = hw >> 6, w = hw & 63;
    size_t ob = ((size_t)(nb * HWN + hw)) * 18 + 2 * k;
    float2 d = *(const float2*)(off + ob);
    float py = (float)(h + k / 3 - 1) + d.x;
    float px = (float)(w + k % 3 - 1) + d.y;
    float fy = floorf(py), fx = floorf(px);
    int iy = (int)fy, ix = (int)fx;
    float wy = py - fy, wx = px - fx;
    float my0 = ((unsigned)iy       < (unsigned)HH) ? 1.f : 0.f;
    float my1 = ((unsigned)(iy + 1) < (unsigned)HH) ? 1.f : 0.f;
    float mx0 = ((unsigned)ix       < (unsigned)WW) ? 1.f : 0.f;
    float mx1 = ((unsigned)(ix + 1) < (unsigned)WW) ? 1.f : 0.f;
    int iy0 = min(max(iy, 0), HH - 1), iy1 = min(max(iy + 1, 0), HH - 1);
    int ix0 = min(max(ix, 0), WW - 1), ix1 = min(max(ix + 1, 0), WW - 1);
    s_po[e] = make_ushort4((unsigned short)(iy0 * WW + ix0),
                           (unsigned short)(iy0 * WW + ix1),
                           (unsigned short)(iy1 * WW + ix0),
                           (unsigned short)(iy1 * WW + ix1));
    s_pw[e] = make_ushort4(f2h((1.f - wy) * (1.f - wx) * my0 * mx0),
                           f2h((1.f - wy) * wx         * my0 * mx1),
                           f2h(wy         * (1.f - wx) * my1 * mx0),
                           f2h(wy         * wx         * my1 * mx1));
  }

  f32x4 acc[2][2];
#pragma unroll
  for (int a = 0; a < 2; ++a)
#pragma unroll
    for (int b = 0; b < 2; ++b) acc[a][b] = (f32x4){0.f, 0.f, 0.f, 0.f};

  const _Float16* xb = xt + (size_t)nb * HWN * CC;
  const int j    = tid & 31;          // channel chunk j*8..j*8+7
  const int slot = tid >> 5;          // pixel slot 0..15

  // sample one tap into buffer bb: 512 thr cover 32 px x 256 c in 2 passes
  auto sample_tap = [&](int kk, int bb) {
#pragma unroll
    for (int i = 0; i < 2; ++i) {
      int p = i * 16 + slot;
      int idx = p * 9 + kk;
      ushort4 o4 = s_po[idx];
      ushort4 hw4 = s_pw[idx];
      half2v w00 = u2h(dupu(hw4.x)), w01 = u2h(dupu(hw4.y));
      half2v w10 = u2h(dupu(hw4.z)), w11 = u2h(dupu(hw4.w));
      const _Float16* cb = xb + (size_t)j * 8;
      uint4 v00 = *(const uint4*)(cb + (size_t)o4.x * CC);
      uint4 v01 = *(const uint4*)(cb + (size_t)o4.y * CC);
      uint4 v10 = *(const uint4*)(cb + (size_t)o4.z * CC);
      uint4 v11 = *(const uint4*)(cb + (size_t)o4.w * CC);
      uint4 r;
      r.x = h2u(u2h(v00.x) * w00 + u2h(v01.x) * w01 + u2h(v10.x) * w10 + u2h(v11.x) * w11);
      r.y = h2u(u2h(v00.y) * w00 + u2h(v01.y) * w01 + u2h(v10.y) * w10 + u2h(v11.y) * w11);
      r.z = h2u(u2h(v00.z) * w00 + u2h(v01.z) * w01 + u2h(v10.z) * w10 + u2h(v11.z) * w11);
      r.w = h2u(u2h(v00.w) * w00 + u2h(v01.w) * w01 + u2h(v10.w) * w10 + u2h(v11.w) * w11);
      *(uint4*)(val_lds + bb * VOFF + p * VST + j * 8) = r;
    }
  };

  __syncthreads();          // params visible
  sample_tap(0, 0);         // prologue: tap 0 into buffer 0

  int cur = 0;
  for (int k = 0; k < 9; ++k) {
    const int nxt = cur ^ 1;

    // ---- issue this tap's 16 B fragment loads (fire-and-forget, cross barrier) ----
    const _Float16* wb = wt + ((size_t)(k * OO + o0)) * CC;
    half8 b0[8], b1[8];
#pragma unroll
    for (int ksg = 0; ksg < 8; ++ksg) {
      b0[ksg] = *(const half8*)(wb + (size_t)(n15)      * CC + ksg * 32 + quad * 8);
      b1[ksg] = *(const half8*)(wb + (size_t)(16 + n15) * CC + ksg * 32 + quad * 8);
    }

    vsync();   // val[cur] published (prev iter's sample); prev GEMM reads done.
               // B loads remain in flight across the barrier (no vmcnt drain).

    // ---- sample next tap into the other buffer (after the barrier: race-free) ----
    if (k < 8) sample_tap(k + 1, nxt);

    // ---- GEMM half 0 (ksg 0..3): pin forces B residency + single bulk wait ----
    asm volatile("" : "+v"(b0[0]), "+v"(b0[1]), "+v"(b0[2]), "+v"(b0[3]),
                      "+v"(b1[0]), "+v"(b1[1]), "+v"(b1[2]), "+v"(b1[3]));
#pragma unroll
    for (int ksg = 0; ksg < 4; ++ksg) {
      half8 afr[2];
#pragma unroll
      for (int mt = 0; mt < 2; ++mt)
        afr[mt] = *(const half8*)(val_lds + cur * VOFF + (mt * 16 + n15) * VST + ksg * 32 + quad * 8);
      acc[0][0] = __builtin_amdgcn_mfma_f32_16x16x32_f16(afr[0], b0[ksg], acc[0][0], 0, 0, 0);
      acc[0][1] = __builtin_amdgcn_mfma_f32_16x16x32_f16(afr[0], b1[ksg], acc[0][1], 0, 0, 0);
      acc[1][0] = __builtin_amdgcn_mfma_f32_16x16x32_f16(afr[1], b0[ksg], acc[1][0], 0, 0, 0);
      acc[1][1] = __builtin_amdgcn_mfma_f32_16x16x32_f16(afr[1], b1[ksg], acc[1][1], 0, 0, 0);
    }

    // ---- GEMM half 1 (ksg 4..7): half1's latency covered by half0 ----
    asm volatile("" : "+v"(b0[4]), "+v"(b0[5]), "+v"(b0[6]), "+v"(b0[7]),
                      "+v"(b1[4]), "+v"(b1[5]), "+v"(b1[6]), "+v"(b1[7]));
#pragma unroll
    for (int ksg = 4; ksg < 8; ++ksg) {
      half8 afr[2];
#pragma unroll
      for (int mt = 0; mt < 2; ++mt)
        afr[mt] = *(const half8*)(val_lds + cur * VOFF + (mt * 16 + n15) * VST + ksg * 32 + quad * 8);
      acc[0][0] = __builtin_amdgcn_mfma_f32_16x16x32_f16(afr[0], b0[ksg], acc[0][0], 0, 0, 0);
      acc[0][1] = __builtin_amdgcn_mfma_f32_16x16x32_f16(afr[0], b1[ksg], acc[0][1], 0, 0, 0);
      acc[1][0] = __builtin_amdgcn_mfma_f32_16x16x32_f16(afr[1], b0[ksg], acc[1][0], 0, 0, 0);
      acc[1][1] = __builtin_amdgcn_mfma_f32_16x16x32_f16(afr[1], b1[ksg], acc[1][1], 0, 0, 0);
    }

    cur = nxt;
  }

  // ---- epilogue: D: col=lane&15 -> o, row=quad*4+reg -> pixel ----
#pragma unroll
  for (int mt = 0; mt < 2; ++mt)
#pragma unroll
    for (int nt = 0; nt < 2; ++nt) {
      int o  = o0 + nt * 16 + n15;
      int px = hw0 + mt * 16 + quad * 4;
      *(f32x4*)(out + ((size_t)nb * OO + o) * HWN + px) = acc[mt][nt];
    }
}

extern "C" void kernel_launch(void* const* d_in, const int* in_sizes, int n_in,
                              void* d_out, int out_size, void* d_ws, size_t ws_size,
                              hipStream_t stream) {
  const float* x   = (const float*)d_in[0];   // [4,256,64,64]
  const float* off = (const float*)d_in[1];   // [4,4096,18]
  const float* w   = (const float*)d_in[2];   // [256,256,3,3]
  float* out = (float*)d_out;                 // [4,256,64,64]

  _Float16* wt = (_Float16*)d_ws;             // 589824 fp16
  _Float16* xt = wt + 589824;                 // 4194304 fp16

  prep_kernel<<<1024 + 256, 256, 0, stream>>>(x, w, xt, wt);
  deform_mfma_kernel<<<512, 512, 0, stream>>>(xt, wt, off, out);
}